// Round 1
// baseline (2260.124 us; speedup 1.0000x reference)
//
#include <hip/hip_runtime.h>

// ============================================================================
// ImprovedMoE: fp32 end-to-end (routing decisions must match np reference
// bit-nearly-exactly; no fp32 MFMA on CDNA4 -> vector-ALU conv trunk).
//
// Workspace layout (floats):
//   wt1..wt6  : conv weights transposed to [ci*9+tap][co]   (1,144,512)
//   bufA      : a1 [512,64,32,32] / a3 [512,128,16,16] / a5 [512,256,8,8]
//   bufB      : a2p [512,64,16,16] / a4p [512,128,8,8]
//   feats,h1,h2,embeds,g1,logits_e,conf,scores
// Total ~192 MB.
// ============================================================================

__global__ void wt_transpose_k(const float* __restrict__ w, float* __restrict__ wt,
                               int CI9, int CO) {
  int n = CI9 * CO;
  int idx = blockIdx.x * 256 + threadIdx.x;
  if (idx < n) {
    int co = idx % CO;
    int r  = idx / CO;            // r = ci*9 + tap
    wt[idx] = w[(size_t)co * CI9 + r];
  }
}

// ---------------------------------------------------------------------------
// Direct 3x3 SAME conv + bias + BN(scale,bias) + ReLU, optional fused pool.
// POOL: 0 = none, 1 = 2x2 maxpool (write H/2 x W/2), 2 = global avg -> feats.
// Weights wt: [CIN][9][COUT] (transposed), read via wave-uniform s_loads.
// Block = 256 threads = 4 waves; wave w handles co-tile [co_blk*4*CO_W + w*CO_W, +CO_W).
// Lane covers PX consecutive x in one row; wave covers WR=64/(W/PX) rows.
// ---------------------------------------------------------------------------
template<int H, int W, int CIN, int COUT, int CO_W, int PX, int CC, int POOL>
__global__ __launch_bounds__(256, 4) void conv3x3(
    const float* __restrict__ in, const float* __restrict__ wt,
    const float* __restrict__ cb, const float* __restrict__ bns,
    const float* __restrict__ bnb, float* __restrict__ out)
{
  constexpr int LPR = W / PX;       // lanes per row
  constexpr int WR  = 64 / LPR;     // rows per wave tile
  constexpr int WP  = W + 4;        // padded LDS row stride (16B aligned)
  constexpr int BLOCK_CO = 4 * CO_W;

  __shared__ float sIn[CC * (WR + 2) * WP];
  __shared__ float sPool[(POOL == 2) ? (BLOCK_CO * 68) : 1];

  const int tid  = threadIdx.x;
  const int lane = tid & 63;
  const int wave = tid >> 6;
  const int b    = blockIdx.x;
  const int co0  = blockIdx.y * BLOCK_CO + wave * CO_W;
  const int co_s = __builtin_amdgcn_readfirstlane(co0);
  const int r0   = blockIdx.z * WR;
  const int row  = lane / LPR;
  const int x0   = (lane % LPR) * PX;

  float acc[PX][CO_W];
#pragma unroll
  for (int p = 0; p < PX; ++p)
#pragma unroll
    for (int j = 0; j < CO_W; ++j) acc[p][j] = 0.f;

  const float* inb = in + (size_t)b * CIN * H * W;

  for (int c0 = 0; c0 < CIN; c0 += CC) {
    const int cc = (CIN - c0 < CC) ? (CIN - c0) : CC;
    // ---- stage input chunk [cc][WR+2][W+2] with zero halo ----
    const int S = cc * (WR + 2) * (W + 2);
    for (int idx = tid; idx < S; idx += 256) {
      int xx = idx % (W + 2);
      int t  = idx / (W + 2);
      int rr = t % (WR + 2);
      int c  = t / (WR + 2);
      int gr = r0 + rr - 1, gx = xx - 1;
      float v = 0.f;
      if (gr >= 0 && gr < H && gx >= 0 && gx < W)
        v = inb[((size_t)(c0 + c) * H + gr) * W + gx];
      sIn[(c * (WR + 2) + rr) * WP + xx] = v;
    }
    __syncthreads();
    // ---- compute ----
    for (int c = 0; c < cc; ++c) {
      const float* lr = &sIn[c * (WR + 2) * WP];
      float rv[3][PX + 2];
#pragma unroll
      for (int dy = 0; dy < 3; ++dy) {
        int base = (row + dy) * WP + x0;
#pragma unroll
        for (int i = 0; i < PX + 2; ++i) rv[dy][i] = lr[base + i];
      }
      const float* wp = wt + ((size_t)(c0 + c) * 9) * COUT + co_s;
#pragma unroll
      for (int t = 0; t < 9; ++t) {
        const int dy = t / 3, dx = t % 3;
        float wreg[CO_W];
#pragma unroll
        for (int j = 0; j < CO_W; ++j) wreg[j] = wp[t * COUT + j];
#pragma unroll
        for (int p = 0; p < PX; ++p) {
          float iv = rv[dy][p + dx];
#pragma unroll
          for (int j = 0; j < CO_W; ++j)
            acc[p][j] = fmaf(iv, wreg[j], acc[p][j]);
        }
      }
    }
    __syncthreads();
  }

  // ---- epilogue: y = (conv + cb)*s + bb = conv*s + (cb*s+bb); relu ----
  const float* cbp = cb + co_s;
  const float* sp  = bns + co_s;
  const float* bp  = bnb + co_s;
  float es[CO_W], eb[CO_W];
#pragma unroll
  for (int j = 0; j < CO_W; ++j) {
    float s_ = sp[j];
    es[j] = s_;
    eb[j] = fmaf(cbp[j], s_, bp[j]);
  }

  if constexpr (POOL == 0) {
    const int r = r0 + row;
#pragma unroll
    for (int j = 0; j < CO_W; ++j) {
      float* op = out + (((size_t)b * COUT + (co0 + j)) * H + r) * W + x0;
      if constexpr (PX >= 4) {
#pragma unroll
        for (int p4 = 0; p4 < PX; p4 += 4) {
          float v0 = fmaxf(fmaf(acc[p4 + 0][j], es[j], eb[j]), 0.f);
          float v1 = fmaxf(fmaf(acc[p4 + 1][j], es[j], eb[j]), 0.f);
          float v2 = fmaxf(fmaf(acc[p4 + 2][j], es[j], eb[j]), 0.f);
          float v3 = fmaxf(fmaf(acc[p4 + 3][j], es[j], eb[j]), 0.f);
          *(float4*)(op + p4) = make_float4(v0, v1, v2, v3);
        }
      } else {
        op[0] = fmaxf(fmaf(acc[0][j], es[j], eb[j]), 0.f);
      }
    }
  } else if constexpr (POOL == 1) {
    const int r = r0 + row;
#pragma unroll
    for (int j = 0; j < CO_W; ++j) {
      float pm[PX / 2];
#pragma unroll
      for (int p2 = 0; p2 < PX / 2; ++p2) {
        float v0 = fmaxf(fmaf(acc[2 * p2][j], es[j], eb[j]), 0.f);
        float v1 = fmaxf(fmaf(acc[2 * p2 + 1][j], es[j], eb[j]), 0.f);
        float m  = fmaxf(v0, v1);
        float om = __shfl_xor(m, LPR, 64);   // partner row (r ^ 1)
        pm[p2]   = fmaxf(m, om);
      }
      if ((row & 1) == 0) {
        float* op = out + (((size_t)b * COUT + (co0 + j)) * (H / 2) + (r >> 1)) * (W / 2) + (x0 >> 1);
        if constexpr (PX / 2 == 4)
          *(float4*)op = make_float4(pm[0], pm[1], pm[2], pm[3]);
        else if constexpr (PX / 2 == 2)
          *(float2*)op = make_float2(pm[0], pm[1]);
        else
          op[0] = pm[0];
      }
    }
  } else {  // POOL == 2: global average over 64 px -> feats[b][COUT]
#pragma unroll
    for (int j = 0; j < CO_W; ++j) {
      float v = fmaxf(fmaf(acc[0][j], es[j], eb[j]), 0.f);
      sPool[(wave * CO_W + j) * 68 + lane] = v;   // lane == pixel index
    }
    __syncthreads();
    if (tid < BLOCK_CO) {
      float s = 0.f;
#pragma unroll
      for (int p = 0; p < 64; p += 4) {
        float4 t4 = *(const float4*)&sPool[tid * 68 + p];
        s += t4.x + t4.y + t4.z + t4.w;
      }
      out[(size_t)b * COUT + blockIdx.y * BLOCK_CO + tid] = s * (1.f / 64.f);
    }
  }
}

// ---------------------------------------------------------------------------
// Batched head GEMM: out[e][b][o] = post( sum_k A[e?][b][k]*W[e][o][k] + bias )
// post: optional LayerNorm over o (g,bb) then optional ReLU.
// Grid (B/64, E). Block 256. Per-thread 4b x (O/16)o accumulators.
// ---------------------------------------------------------------------------
template<int O, int K, int LN, int RELU>
__global__ __launch_bounds__(256, 4) void gemm_head(
    const float* __restrict__ A, size_t aStrideE,
    const float* __restrict__ Wm, const float* __restrict__ bias,
    const float* __restrict__ g, const float* __restrict__ bb,
    float* __restrict__ out)
{
  constexpr int KC  = (O >= 256) ? 32 : 64;
  constexpr int WST = O + 4;
  constexpr int TO  = O / 16;
  __shared__ float sA[KC * 68];
  __shared__ float sW[KC * WST];
  __shared__ float mArr[64], rArr[64];

  const int tid  = threadIdx.x;
  const int lane = tid & 63;
  const int wave = tid >> 6;
  const int e    = blockIdx.y;
  const int b0g  = blockIdx.x * 64;
  const int bl   = (lane & 15) * 4;                      // local b base
  const int ol   = wave * (O / 4) + (lane >> 4) * TO;    // o base

  const float* Ae = A + (size_t)e * aStrideE;
  const float* We = Wm + (size_t)e * O * K;

  float acc[4][TO];
#pragma unroll
  for (int i = 0; i < 4; ++i)
#pragma unroll
    for (int j = 0; j < TO; ++j) acc[i][j] = 0.f;

  for (int k0 = 0; k0 < K; k0 += KC) {
    for (int idx = tid; idx < 64 * KC; idx += 256) {
      int kk = idx % KC, bb_ = idx / KC;
      sA[kk * 68 + bb_] = Ae[(size_t)(b0g + bb_) * K + k0 + kk];
    }
    for (int idx = tid; idx < O * KC; idx += 256) {
      int kk = idx % KC, oo = idx / KC;
      sW[kk * WST + oo] = We[(size_t)oo * K + k0 + kk];
    }
    __syncthreads();
#pragma unroll 4
    for (int kk = 0; kk < KC; ++kk) {
      float4 av = *(const float4*)&sA[kk * 68 + bl];
      float a4[4] = {av.x, av.y, av.z, av.w};
#pragma unroll
      for (int j4 = 0; j4 < TO; j4 += 4) {
        float4 wv = *(const float4*)&sW[kk * WST + ol + j4];
        float w4[4] = {wv.x, wv.y, wv.z, wv.w};
#pragma unroll
        for (int i = 0; i < 4; ++i)
#pragma unroll
          for (int jj = 0; jj < 4; ++jj)
            acc[i][j4 + jj] = fmaf(a4[i], w4[jj], acc[i][j4 + jj]);
      }
    }
    __syncthreads();
  }

  const float* bi = bias + (size_t)e * O;
#pragma unroll
  for (int i = 0; i < 4; ++i)
#pragma unroll
    for (int j = 0; j < TO; ++j) acc[i][j] += bi[ol + j];

  if constexpr (LN) {
    float* redS = sA;          // reuse staging LDS (>= 2048 floats)
    float* redQ = sA + 1024;
    const int grp = wave * 4 + (lane >> 4);   // 0..15, which o-range
#pragma unroll
    for (int i = 0; i < 4; ++i) {
      float s = 0.f, q = 0.f;
#pragma unroll
      for (int j = 0; j < TO; ++j) { s += acc[i][j]; q += acc[i][j] * acc[i][j]; }
      redS[(bl + i) * 16 + grp] = s;
      redQ[(bl + i) * 16 + grp] = q;
    }
    __syncthreads();
    if (tid < 64) {
      float s = 0.f, q = 0.f;
#pragma unroll
      for (int gi = 0; gi < 16; ++gi) { s += redS[tid * 16 + gi]; q += redQ[tid * 16 + gi]; }
      float mean = s * (1.f / O);
      float var  = q * (1.f / O) - mean * mean;
      mArr[tid] = mean;
      rArr[tid] = rsqrtf(var + 1e-5f);
    }
    __syncthreads();
    const float* gp  = g + (size_t)e * O;
    const float* bbp = bb + (size_t)e * O;
#pragma unroll
    for (int i = 0; i < 4; ++i) {
      float mean = mArr[bl + i], rstd = rArr[bl + i];
#pragma unroll
      for (int j = 0; j < TO; ++j)
        acc[i][j] = (acc[i][j] - mean) * rstd * gp[ol + j] + bbp[ol + j];
    }
  }
  if constexpr (RELU) {
#pragma unroll
    for (int i = 0; i < 4; ++i)
#pragma unroll
      for (int j = 0; j < TO; ++j) acc[i][j] = fmaxf(acc[i][j], 0.f);
  }
#pragma unroll
  for (int i = 0; i < 4; ++i) {
    float* op = out + ((size_t)e * 512 + b0g + bl + i) * O + ol;
#pragma unroll
    for (int j4 = 0; j4 < TO; j4 += 4)
      *(float4*)(op + j4) = make_float4(acc[i][j4], acc[i][j4 + 1], acc[i][j4 + 2], acc[i][j4 + 3]);
  }
}

// ---------------------------------------------------------------------------
// cls: logits_e[b][e][o<10] = embeds[e][b][:128] . cls_w[e][o][:] + cls_b
// + softmax + entropy -> conf[b][e] = -entropy. One wave per (b,e).
// ---------------------------------------------------------------------------
__global__ void cls_softmax_k(const float* __restrict__ embeds,
                              const float* __restrict__ cw,
                              const float* __restrict__ cbias,
                              float* __restrict__ logits_e,
                              float* __restrict__ conf)
{
  int wv   = (blockIdx.x * 256 + threadIdx.x) >> 6;
  int lane = threadIdx.x & 63;
  int b = wv >> 4, e = wv & 15;
  const float* ep = embeds + ((size_t)e * 512 + b) * 128;
  float e0 = ep[lane], e1 = ep[lane + 64];
  float l[10];
#pragma unroll
  for (int o = 0; o < 10; ++o) {
    const float* wp = cw + ((size_t)e * 10 + o) * 128;
    l[o] = e0 * wp[lane] + e1 * wp[lane + 64];
  }
#pragma unroll
  for (int s = 32; s >= 1; s >>= 1)
#pragma unroll
    for (int o = 0; o < 10; ++o) l[o] += __shfl_xor(l[o], s, 64);
#pragma unroll
  for (int o = 0; o < 10; ++o) l[o] += cbias[e * 10 + o];
  float m = l[0];
#pragma unroll
  for (int o = 1; o < 10; ++o) m = fmaxf(m, l[o]);
  float p[10], sum = 0.f;
#pragma unroll
  for (int o = 0; o < 10; ++o) { p[o] = expf(l[o] - m); sum += p[o]; }
  float inv = 1.f / sum, ent = 0.f;
#pragma unroll
  for (int o = 0; o < 10; ++o) { float pp = p[o] * inv; ent -= pp * logf(pp + 1e-12f); }
  if (lane == 0) {
    conf[b * 16 + e] = -ent;
#pragma unroll
    for (int o = 0; o < 10; ++o) logits_e[((size_t)b * 16 + e) * 10 + o] = l[o];
  }
}

// ---------------------------------------------------------------------------
// gates 2+3: g2 = relu(g1 . w2 + b2) [32]; scores = g2 . w3 + b3. Wave per (b,e).
// ---------------------------------------------------------------------------
__global__ void gate23_k(const float* __restrict__ g1, const float* __restrict__ w2,
                         const float* __restrict__ b2, const float* __restrict__ w3,
                         const float* __restrict__ b3, float* __restrict__ scores)
{
  int wv   = (blockIdx.x * 256 + threadIdx.x) >> 6;
  int lane = threadIdx.x & 63;
  int b = wv >> 4, e = wv & 15;
  float gv = g1[((size_t)e * 512 + b) * 64 + lane];
  const float* w3p = w3 + e * 32;
  float sc = 0.f;
#pragma unroll
  for (int o = 0; o < 32; ++o) {
    float t = gv * w2[((size_t)e * 32 + o) * 64 + lane];
#pragma unroll
    for (int s = 32; s >= 1; s >>= 1) t += __shfl_xor(t, s, 64);
    float g2v = fmaxf(t + b2[e * 32 + o], 0.f);
    sc = fmaf(g2v, w3p[o], sc);
  }
  if (lane == 0) scores[b * 16 + e] = sc + b3[e];   // RTEMP == 1
}

// ---------------------------------------------------------------------------
// Routing: balanced = 0.7*scores + 0.3*conf - 0.125 (usage bonus is 0 at init).
// top-2 per row, sequential capacity scan (CAP=64), outputs.
// One block of 512 threads; scan done by wave 0 with loads in lane registers.
// ---------------------------------------------------------------------------
__global__ void routing_k(const float* __restrict__ scores, const float* __restrict__ conf,
                          const float* __restrict__ logits_e, float* __restrict__ out)
{
  __shared__ int t2[512];
  __shared__ int chs[512];
  const int tid = threadIdx.x;

  if (tid < 512) {
    int b = tid;
    float bal[16];
    float v0 = -3.4e38f, v1 = -3.4e38f;
    int i0 = 0, i1 = 0;
#pragma unroll
    for (int e = 0; e < 16; ++e) {
      float s = scores[b * 16 + e];
      float c = conf[b * 16 + e];
      float v = 0.7f * s + 0.3f * c - 0.125f;
      bal[e] = v;
      out[5120 + b * 16 + e] = v;   // balanced output
      if (v > v0) { v1 = v0; i1 = i0; v0 = v; i0 = e; }
      else if (v > v1) { v1 = v; i1 = e; }
    }
    (void)bal;
    t2[b] = i0 | (i1 << 8);
  }
  __syncthreads();

  if (tid < 64) {
    int lane = tid;
    int cnt = 0;
    int pk[8];
#pragma unroll
    for (int k = 0; k < 8; ++k) pk[k] = t2[k * 64 + lane];
#pragma unroll 1
    for (int k = 0; k < 8; ++k) {
      for (int j = 0; j < 64; ++j) {
        int pair = __shfl(pk[k], j, 64);
        int i0 = pair & 0xff, i1 = (pair >> 8) & 0xff;
        int c0 = __shfl(cnt, i0, 64);
        int c1 = __shfl(cnt, i1, 64);
        int ch = (c0 < 64) ? i0 : ((c1 < 64) ? i1 : ((c0 <= c1) ? i0 : i1));
        cnt += (lane == ch) ? 1 : 0;
        if (lane == 0) chs[k * 64 + j] = ch;
      }
    }
  }
  __syncthreads();

  if (tid < 512) {
    int b = tid;
    int ch = chs[b];
#pragma unroll
    for (int e = 0; e < 16; ++e)
      out[13312 + b * 16 + e] = (e == ch) ? 1.0f : 0.0f;   // D
#pragma unroll
    for (int o = 0; o < 10; ++o)
      out[b * 10 + o] = logits_e[((size_t)b * 16 + ch) * 10 + o];  // final_logits
  }
}

// ============================================================================
extern "C" void kernel_launch(void* const* d_in, const int* in_sizes, int n_in,
                              void* d_out, int out_size, void* d_ws, size_t ws_size,
                              hipStream_t stream) {
  (void)in_sizes; (void)n_in; (void)out_size; (void)ws_size;

  const float* x = (const float*)d_in[0];
  const float *cw[6], *cbv[6], *bsv[6], *bbv[6];
  for (int i = 0; i < 6; ++i) {
    cw[i]  = (const float*)d_in[1 + 4 * i];
    cbv[i] = (const float*)d_in[2 + 4 * i];
    bsv[i] = (const float*)d_in[3 + 4 * i];
    bbv[i] = (const float*)d_in[4 + 4 * i];
  }
  const float* gate_w1  = (const float*)d_in[25];
  const float* gate_b1  = (const float*)d_in[26];
  const float* gate_g1  = (const float*)d_in[27];
  const float* gate_bb1 = (const float*)d_in[28];
  const float* gate_w2  = (const float*)d_in[29];
  const float* gate_b2  = (const float*)d_in[30];
  const float* gate_w3  = (const float*)d_in[31];
  const float* gate_b3  = (const float*)d_in[32];
  const float* exp_w1   = (const float*)d_in[33];
  const float* exp_b1   = (const float*)d_in[34];
  const float* exp_g1   = (const float*)d_in[35];
  const float* exp_bb1  = (const float*)d_in[36];
  const float* exp_w2   = (const float*)d_in[37];
  const float* exp_b2   = (const float*)d_in[38];
  const float* exp_g2   = (const float*)d_in[39];
  const float* exp_bb2  = (const float*)d_in[40];
  const float* exp_w3   = (const float*)d_in[41];
  const float* exp_b3   = (const float*)d_in[42];
  const float* cls_w    = (const float*)d_in[43];
  const float* cls_b    = (const float*)d_in[44];

  float* ws = (float*)d_ws;
  size_t o_wt1 = 0;
  size_t o_wt2 = o_wt1 + 1728;
  size_t o_wt3 = o_wt2 + 36864;
  size_t o_wt4 = o_wt3 + 73728;
  size_t o_wt5 = o_wt4 + 147456;
  size_t o_wt6 = o_wt5 + 294912;
  size_t o_bufA  = o_wt6 + 589824;
  size_t o_bufB  = o_bufA + 33554432ull;
  size_t o_feats = o_bufB + 8388608ull;
  size_t o_h1    = o_feats + 131072;
  size_t o_h2    = o_h1 + 2097152;
  size_t o_emb   = o_h2 + 1048576;
  size_t o_g1    = o_emb + 1048576;
  size_t o_lg    = o_g1 + 524288;
  size_t o_conf  = o_lg + 81920;
  size_t o_sc    = o_conf + 8192;

  float* wt1 = ws + o_wt1; float* wt2 = ws + o_wt2; float* wt3 = ws + o_wt3;
  float* wt4 = ws + o_wt4; float* wt5 = ws + o_wt5; float* wt6 = ws + o_wt6;
  float* bufA = ws + o_bufA; float* bufB = ws + o_bufB;
  float* feats = ws + o_feats; float* h1 = ws + o_h1; float* h2 = ws + o_h2;
  float* emb = ws + o_emb; float* g1 = ws + o_g1; float* lg = ws + o_lg;
  float* conf = ws + o_conf; float* sc = ws + o_sc;

  auto cdiv = [](int a, int b) { return (a + b - 1) / b; };

  // ---- weight transposes ----
  wt_transpose_k<<<cdiv(27 * 64, 256), 256, 0, stream>>>(cw[0], wt1, 27, 64);
  wt_transpose_k<<<cdiv(576 * 64, 256), 256, 0, stream>>>(cw[1], wt2, 576, 64);
  wt_transpose_k<<<cdiv(576 * 128, 256), 256, 0, stream>>>(cw[2], wt3, 576, 128);
  wt_transpose_k<<<cdiv(1152 * 128, 256), 256, 0, stream>>>(cw[3], wt4, 1152, 128);
  wt_transpose_k<<<cdiv(1152 * 256, 256), 256, 0, stream>>>(cw[4], wt5, 1152, 256);
  wt_transpose_k<<<cdiv(2304 * 256, 256), 256, 0, stream>>>(cw[5], wt6, 2304, 256);

  // ---- trunk ----
  conv3x3<32, 32, 3, 64, 8, 8, 3, 0><<<dim3(512, 2, 2), 256, 0, stream>>>(
      x, wt1, cbv[0], bsv[0], bbv[0], bufA);
  conv3x3<32, 32, 64, 64, 8, 8, 8, 1><<<dim3(512, 2, 2), 256, 0, stream>>>(
      bufA, wt2, cbv[1], bsv[1], bbv[1], bufB);
  conv3x3<16, 16, 64, 128, 16, 4, 8, 0><<<dim3(512, 2, 1), 256, 0, stream>>>(
      bufB, wt3, cbv[2], bsv[2], bbv[2], bufA);
  conv3x3<16, 16, 128, 128, 16, 4, 8, 1><<<dim3(512, 2, 1), 256, 0, stream>>>(
      bufA, wt4, cbv[3], bsv[3], bbv[3], bufB);
  conv3x3<8, 8, 128, 256, 32, 1, 8, 0><<<dim3(512, 2, 1), 256, 0, stream>>>(
      bufB, wt5, cbv[4], bsv[4], bbv[4], bufA);
  conv3x3<8, 8, 256, 256, 32, 1, 8, 2><<<dim3(512, 2, 1), 256, 0, stream>>>(
      bufA, wt6, cbv[5], bsv[5], bbv[5], feats);

  // ---- experts ----
  gemm_head<256, 256, 1, 1><<<dim3(8, 16), 256, 0, stream>>>(
      feats, (size_t)0, exp_w1, exp_b1, exp_g1, exp_bb1, h1);
  gemm_head<128, 256, 1, 1><<<dim3(8, 16), 256, 0, stream>>>(
      h1, (size_t)512 * 256, exp_w2, exp_b2, exp_g2, exp_bb2, h2);
  gemm_head<128, 128, 0, 0><<<dim3(8, 16), 256, 0, stream>>>(
      h2, (size_t)512 * 128, exp_w3, exp_b3, nullptr, nullptr, emb);
  cls_softmax_k<<<2048, 256, 0, stream>>>(emb, cls_w, cls_b, lg, conf);

  // ---- gates ----
  gemm_head<64, 256, 1, 1><<<dim3(8, 16), 256, 0, stream>>>(
      feats, (size_t)0, gate_w1, gate_b1, gate_g1, gate_bb1, g1);
  gate23_k<<<2048, 256, 0, stream>>>(g1, gate_w2, gate_b2, gate_w3, gate_b3, sc);

  // ---- routing + outputs ----
  routing_k<<<1, 512, 0, stream>>>(sc, conf, lg, (float*)d_out);
}